// Round 9
// baseline (49.228 us; speedup 1.0000x reference)
//
#include <hip/hip_runtime.h>

// Problem constants (B,H,S,D) = (2,32,2048,128); HIDDEN = 4096
constexpr int D = 128;
constexpr int H = 32;
constexpr int S = 2048;
constexpr float HAD_SCALE_F = 0.08838834764831845f; // RN32(1/sqrt(128))

// In-register f32 FWHT of a 128-element row held as float4 across 32 lanes.
// Lane (l&31) holds elements e = 4*(l&31)+j. Butterfly order identical to ref.
__device__ __forceinline__ void fwht128_f32(float4& v, int l) {
    float a0 = v.x + v.y;
    float a1 = v.x - v.y;
    float a2 = v.z + v.w;
    float a3 = v.z - v.w;
    v.x = a0 + a2;
    v.y = a1 + a3;
    v.z = a0 - a2;
    v.w = a1 - a3;
    #pragma unroll
    for (int m = 1; m <= 16; m <<= 1) {
        const bool up = (l & m) != 0;
        float ox = __shfl_xor(v.x, m);
        float oy = __shfl_xor(v.y, m);
        float oz = __shfl_xor(v.z, m);
        float ow = __shfl_xor(v.w, m);
        v.x = up ? (ox - v.x) : (v.x + ox);
        v.y = up ? (oy - v.y) : (v.y + oy);
        v.z = up ? (oz - v.z) : (v.z + oz);
        v.w = up ? (ow - v.w) : (v.w + ow);
    }
    v.x *= HAD_SCALE_F;
    v.y *= HAD_SCALE_F;
    v.z *= HAD_SCALE_F;
    v.w *= HAD_SCALE_F;
}

// q: pure per-row f32 WHT. One wave handles 2 rows. (PASSES — untouched.)
__global__ __launch_bounds__(256) void had_q(const float* __restrict__ in,
                                             float* __restrict__ out) {
    const int gtid = blockIdx.x * 256 + threadIdx.x;
    const int gw = gtid >> 6;
    const int l  = gtid & 63;
    const int il = l & 31;
    const long long row = 2LL * gw + (l >> 5);
    float4 v = reinterpret_cast<const float4*>(in + row * D)[il];
    fwht128_f32(v, l);
    reinterpret_cast<float4*>(out + row * D)[il] = v;
}

// Fast-math-golden fake-quant: quotient via multiply-by-correctly-rounded
// reciprocal (LLVM arcp rewrite of x/scale with hoisted 1/scale), rintf
// (half-even), clip [-8,7], dequant f32.
__device__ __forceinline__ float fq_rcp(float x, float rs, float scale) {
    float quot = x * rs;                 // RN32(x * RN32(1/scale))
    float qf = rintf(quot);
    qf = fminf(fmaxf(qf, -8.f), 7.f);
    return qf * scale;
}

// k: f32 WHT of all 32 heads of one token, f32 block absmax, reciprocal-based
// f32 quant, store in (B,H,S,D). One block per token.
__global__ __launch_bounds__(256) void had_quant_k(const float* __restrict__ in,
                                                   float* __restrict__ out) {
    __shared__ float smax[4];
    const int token = blockIdx.x;        // b*S + s
    const int tid = threadIdx.x;
    const int wv = tid >> 6;
    const int l  = tid & 63;
    const int il = l & 31;
    const int half = l >> 5;
    const long long b = token >> 11;     // S = 2048
    const long long s = token & (S - 1);

    float4 vals[4];
    float m = 0.f;
    #pragma unroll
    for (int it = 0; it < 4; ++it) {
        const int h = wv * 8 + it * 2 + half;
        const long long rowoff = ((b * H + h) * (long long)S + s) * D;
        float4 v = reinterpret_cast<const float4*>(in + rowoff)[il];
        fwht128_f32(v, l);
        vals[it] = v;
        m = fmaxf(m, fmaxf(fmaxf(fabsf(v.x), fabsf(v.y)),
                           fmaxf(fabsf(v.z), fabsf(v.w))));
    }
    #pragma unroll
    for (int mm = 1; mm < 64; mm <<= 1)
        m = fmaxf(m, __shfl_xor(m, mm));
    if (l == 0) smax[wv] = m;
    __syncthreads();
    m = fmaxf(fmaxf(smax[0], smax[1]), fmaxf(smax[2], smax[3]));

    // fast-math lowering of the reference's two divisions:
    //   scale = xmax/7  ->  xmax * RN32(1/7)
    //   x/scale         ->  x * RN32(1/scale)   (reciprocal hoisted per row)
    const float xmax = m * 0.95f;                        // K_CLIP
    constexpr float INV7 = 1.0f / 7.0f;                  // RN32(1/7)
    const float scale = (xmax == 0.f) ? 1.f : (xmax * INV7);
    const float rs = (float)(1.0 / (double)scale);       // RN32(1/scale), IEEE

    #pragma unroll
    for (int it = 0; it < 4; ++it) {
        const int h = wv * 8 + it * 2 + half;
        const long long rowoff = ((b * H + h) * (long long)S + s) * D;
        float4 v = vals[it];
        float4 o;
        o.x = fq_rcp(v.x, rs, scale);
        o.y = fq_rcp(v.y, rs, scale);
        o.z = fq_rcp(v.z, rs, scale);
        o.w = fq_rcp(v.w, rs, scale);
        reinterpret_cast<float4*>(out + rowoff)[il] = o;
    }
}

extern "C" void kernel_launch(void* const* d_in, const int* in_sizes, int n_in,
                              void* d_out, int out_size, void* d_ws, size_t ws_size,
                              hipStream_t stream) {
    const float* q = (const float*)d_in[0];
    const float* k = (const float*)d_in[1];
    float* out = (float*)d_out;
    const long long qelems = 2LL * H * S * D;   // 16,777,216

    had_q<<<16384, 256, 0, stream>>>(q, out);
    had_quant_k<<<4096, 256, 0, stream>>>(k, out + qelems);
}

// Round 10
// 46.465 us; speedup vs baseline: 1.0595x; 1.0595x over previous
//
#include <hip/hip_runtime.h>

// Problem constants (B,H,S,D) = (2,32,2048,128); HIDDEN = 4096
constexpr int D = 128;
constexpr int H = 32;
constexpr int S = 2048;
constexpr float HAD_SCALE_F = 0.08838834764831845f; // RN32(1/sqrt(128))

constexpr int K_BLOCKS = 4096;    // one per token (B*S)
constexpr int Q_BLOCKS = 16384;   // 131072 q-rows / 8 rows per block

// In-register f32 FWHT of a 128-element row held as float4 across 32 lanes.
// Lane (l&31) holds elements e = 4*(l&31)+j. Butterfly order identical to ref.
__device__ __forceinline__ void fwht128_f32(float4& v, int l) {
    float a0 = v.x + v.y;
    float a1 = v.x - v.y;
    float a2 = v.z + v.w;
    float a3 = v.z - v.w;
    v.x = a0 + a2;
    v.y = a1 + a3;
    v.z = a0 - a2;
    v.w = a1 - a3;
    #pragma unroll
    for (int m = 1; m <= 16; m <<= 1) {
        const bool up = (l & m) != 0;
        float ox = __shfl_xor(v.x, m);
        float oy = __shfl_xor(v.y, m);
        float oz = __shfl_xor(v.z, m);
        float ow = __shfl_xor(v.w, m);
        v.x = up ? (ox - v.x) : (v.x + ox);
        v.y = up ? (oy - v.y) : (v.y + oy);
        v.z = up ? (oz - v.z) : (v.z + oz);
        v.w = up ? (ow - v.w) : (v.w + ow);
    }
    v.x *= HAD_SCALE_F;
    v.y *= HAD_SCALE_F;
    v.z *= HAD_SCALE_F;
    v.w *= HAD_SCALE_F;
}

// Fake-quant matching the golden's fast-math lowering: quotient via
// multiply-by-reciprocal, rintf (half-even), clip [-8,7], dequant f32.
__device__ __forceinline__ float fq_rcp(float x, float rs, float scale) {
    float quot = x * rs;                 // RN32(x * RN32(1/scale))
    float qf = rintf(quot);
    qf = fminf(fmaxf(qf, -8.f), 7.f);
    return qf * scale;
}

// Fused kernel. Blocks [0, K_BLOCKS) do the k path (heavier — scheduled
// first so q blocks backfill the tail); blocks [K_BLOCKS, K_BLOCKS+Q_BLOCKS)
// do the q path. Arithmetic identical to the R9 passing kernel (bit-exact).
__global__ __launch_bounds__(256) void had_qk(const float* __restrict__ qin,
                                              const float* __restrict__ kin,
                                              float* __restrict__ qout,
                                              float* __restrict__ kout) {
    const int tid = threadIdx.x;
    const int l  = tid & 63;
    const int il = l & 31;

    if (blockIdx.x >= K_BLOCKS) {
        // ---------------- q path: pure per-row f32 WHT ----------------
        const int qb = blockIdx.x - K_BLOCKS;
        const int gw = qb * 4 + (tid >> 6);          // global wave id
        const long long row = 2LL * gw + (l >> 5);
        float4 v = reinterpret_cast<const float4*>(qin + row * D)[il];
        fwht128_f32(v, l);
        reinterpret_cast<float4*>(qout + row * D)[il] = v;
        return;
    }

    // ---------------- k path: WHT + per-token fake-quant ----------------
    __shared__ float smax[4];
    const int token = blockIdx.x;        // b*S + s
    const int wv = tid >> 6;
    const int half = l >> 5;
    const long long b = token >> 11;     // S = 2048
    const long long s = token & (S - 1);

    float4 vals[4];
    float m = 0.f;
    #pragma unroll
    for (int it = 0; it < 4; ++it) {
        const int h = wv * 8 + it * 2 + half;
        const long long rowoff = ((b * H + h) * (long long)S + s) * D;
        float4 v = reinterpret_cast<const float4*>(kin + rowoff)[il];
        fwht128_f32(v, l);
        vals[it] = v;
        m = fmaxf(m, fmaxf(fmaxf(fabsf(v.x), fabsf(v.y)),
                           fmaxf(fabsf(v.z), fabsf(v.w))));
    }
    #pragma unroll
    for (int mm = 1; mm < 64; mm <<= 1)
        m = fmaxf(m, __shfl_xor(m, mm));
    if (l == 0) smax[wv] = m;
    __syncthreads();
    m = fmaxf(fmaxf(smax[0], smax[1]), fmaxf(smax[2], smax[3]));

    // fast-math lowering of the reference's two divisions:
    //   scale = xmax/7  ->  xmax * RN32(1/7)
    //   x/scale         ->  x * RN32(1/scale)   (reciprocal hoisted)
    const float xmax = m * 0.95f;                        // K_CLIP
    constexpr float INV7 = 1.0f / 7.0f;                  // RN32(1/7)
    const float scale = (xmax == 0.f) ? 1.f : (xmax * INV7);
    const float rs = (float)(1.0 / (double)scale);       // RN32(1/scale), IEEE

    #pragma unroll
    for (int it = 0; it < 4; ++it) {
        const int h = wv * 8 + it * 2 + half;
        const long long rowoff = ((b * H + h) * (long long)S + s) * D;
        float4 v = vals[it];
        float4 o;
        o.x = fq_rcp(v.x, rs, scale);
        o.y = fq_rcp(v.y, rs, scale);
        o.z = fq_rcp(v.z, rs, scale);
        o.w = fq_rcp(v.w, rs, scale);
        reinterpret_cast<float4*>(kout + rowoff)[il] = o;
    }
}

extern "C" void kernel_launch(void* const* d_in, const int* in_sizes, int n_in,
                              void* d_out, int out_size, void* d_ws, size_t ws_size,
                              hipStream_t stream) {
    const float* q = (const float*)d_in[0];
    const float* k = (const float*)d_in[1];
    float* out = (float*)d_out;
    const long long qelems = 2LL * H * S * D;   // 16,777,216

    had_qk<<<K_BLOCKS + Q_BLOCKS, 256, 0, stream>>>(q, k, out, out + qelems);
}